// Round 10
// baseline (288.339 us; speedup 1.0000x reference)
//
#include <hip/hip_runtime.h>

// SemanticCaps dynamic routing, fp32. B=128, J=10, K=1152, M=16, I=8.
// R14: vector-Ws + cheap-softmax quadrant. Wave = output capsule j (10
// waves/block), lane = (b4, m) [4 batches x 16 m-lanes]. Ws rows are
// per-lane distinct -> true coalesced vector loads (NO scalar-cache/SGPR
// chunk serialization — the R5..R11 structure's hidden stall; NO LDS-pipe
// broadcast cost — R6's dead end). Logit = 4 width-16 shuffles; den via
// the proven per-k earr ping-pong (1 barrier/k). Per-thread state ~6
// scalars -> ~40 VGPR, grid (128,32) = 4096 blocks -> ~3 blocks/CU of
// INDEPENDENT barrier convoys covering each other's stalls.
// Falsified: Ws scalar stalls unfixable in-SGPR (R11), LDS-Ws (R6),
// m-lane shuffle-heavy layout (R12/R13), grid-sync (R3/R10), atomics
// (R4/R8), forced occupancy caps (R12).
// b-logit algebra: b after t iters = u.(v0+..+v_{t-1}) (b starts at 0).
//
// ws (floats): sp[128*10*128*16] v0T[20480] vsumT[20480]

#define B_ 128
#define J_ 10
#define K_ 1152
#define M_ 16
#define I_ 8
#define KT 9
#define NKT (K_ / KT)        // 128 k-tiles
#define RW (K_ * I_)         // 9216 floats per x batch-row
#define SVEC (J_ * B_ * M_)  // 20480 floats per fold-slice of sp

// ---------- routing pass -----------------------------------------------------
// MODE 0: c == 1 (iteration 0; 0.1 folded into squash<0>)
// MODE 1: c = softmax_j(u . vin);  s = sum_k c*u
// grid (NKT, 32), block 640 = 10 waves (j) x [b4 (lane>>4) x m (lane&15)].
// Thread owns one (j, b, m): u is a SCALAR per k; s is ONE accumulator.
template <int MODE>
__global__ __launch_bounds__(640)
void iter_kernel(const float* __restrict__ x, const float* __restrict__ Ws,
                 const float* __restrict__ vinT, float* __restrict__ sp) {
    __shared__ float earr[2][J_ * 64];
    const int t  = threadIdx.x;
    const int l  = t & 63;
    const int j  = t >> 6;           // wave = j
    const int m  = l & 15;           // m-lane (low bits -> width-16 shuffles)
    const int b4 = l >> 4;           // 0..3
    const int kt = blockIdx.x, bq = blockIdx.y;
    const int b  = bq * 4 + b4;

    float v = 0.f;
    if (MODE == 1) v = vinT[((size_t)j * B_ + b) * M_ + m];   // vT layout [j][b][m]
    float s = 0.f;

    const float* xrow = x + (size_t)b * RW + (size_t)kt * KT * I_;       // 16-lane broadcast
    const float* wrow = Ws + ((size_t)j * K_ + (size_t)kt * KT) * (M_ * I_) + m * I_;  // coalesced

    for (int kk = 0; kk < KT; ++kk) {
        const float4 xa = *(const float4*)(xrow + kk * I_);
        const float4 xb = *(const float4*)(xrow + kk * I_ + 4);
        const float4 wa = *(const float4*)(wrow + (size_t)kk * (M_ * I_));
        const float4 wb = *(const float4*)(wrow + (size_t)kk * (M_ * I_) + 4);
        const float u = wa.x * xa.x + wa.y * xa.y + wa.z * xa.z + wa.w * xa.w
                      + wb.x * xb.x + wb.y * xb.y + wb.z * xb.z + wb.w * xb.w;

        if (MODE == 1) {
            float p = u * v;                  // dot over m: 16-lane tree sum
            p += __shfl_xor(p, 1, 16);
            p += __shfl_xor(p, 2, 16);
            p += __shfl_xor(p, 4, 16);
            p += __shfl_xor(p, 8, 16);
            const float e = __expf(p);
            earr[kk & 1][j * 64 + l] = e;
            __syncthreads();                  // one barrier/k; ping-pong safe
            float den = 0.f;
#pragma unroll
            for (int jj = 0; jj < J_; ++jj) den += earr[kk & 1][jj * 64 + l];
            s = fmaf(__fdividef(e, den), u, s);
        } else {
            s += u;
        }
    }

    sp[(((size_t)kt * J_ + j) * B_ + b) * M_ + m] = s;   // 256 B/wave contiguous
}

// ---------- squash: parallel fold of 128 tile-partials, emit v ---------------
// 320 blocks x 256 thr; 4 waves each fold 32 slices for 64 outputs, LDS fold,
// wave 0 does the m-shuffle norm + emit.
// SM 0: v0T = squash(0.1*S)  SM 1: vsumT = v0T + squash(S)  SM 2: out = squash(S)
template <int SM>
__global__ __launch_bounds__(256)
void squash_kernel(const float* __restrict__ sp, const float* __restrict__ v0T,
                   float* __restrict__ dst) {
    __shared__ float red[4][64];
    const int t  = threadIdx.x;
    const int l  = t & 63;
    const int wv = t >> 6;
    const int g  = blockIdx.x * 64 + l;   // g = (j*128+b)*16+m
    const int m = g & 15;
    const int b = (g >> 4) & 127;
    const int j = g >> 11;
    const float* p = sp + (size_t)((j * B_ + b) * M_ + m);
    float S = 0.f;
#pragma unroll 8
    for (int tt = wv * (NKT / 4); tt < (wv + 1) * (NKT / 4); ++tt)
        S += p[(size_t)tt * SVEC];
    red[wv][l] = S;
    __syncthreads();
    if (wv == 0) {
        S = red[0][l] + red[1][l] + red[2][l] + red[3][l];
        if (SM == 0) S *= 0.1f;
        float sq = S * S;
        sq += __shfl_xor(sq, 1, 64);
        sq += __shfl_xor(sq, 2, 64);
        sq += __shfl_xor(sq, 4, 64);
        sq += __shfl_xor(sq, 8, 64);      // sum over m within 16-lane group
        const float n = sqrtf(sq);
        float v = S * (n / (1.f + sq));
        if (SM == 1) v += v0T[g];
        if (SM == 2) dst[((size_t)b * J_ + j) * M_ + m] = v;   // standard [b][j][m]
        else         dst[g] = v;                                // vT layout
    }
}

extern "C" void kernel_launch(void* const* d_in, const int* in_sizes, int n_in,
                              void* d_out, int out_size, void* d_ws, size_t ws_size,
                              hipStream_t stream) {
    const float* x  = (const float*)d_in[0];   // [128][1152][8]
    const float* Ws = (const float*)d_in[1];   // [10][1152][16][8]
    float* out = (float*)d_out;                // [128][10][16]

    float* sp    = (float*)d_ws;                           // 2,621,440 floats
    float* v0T   = sp + (size_t)NKT * SVEC;                //    20,480
    float* vsumT = v0T + SVEC;                             //    20,480

    iter_kernel<0><<<dim3(NKT, 32), 640, 0, stream>>>(x, Ws, nullptr, sp);
    squash_kernel<0><<<320, 256, 0, stream>>>(sp, nullptr, v0T);

    iter_kernel<1><<<dim3(NKT, 32), 640, 0, stream>>>(x, Ws, v0T, sp);
    squash_kernel<1><<<320, 256, 0, stream>>>(sp, v0T, vsumT);

    iter_kernel<1><<<dim3(NKT, 32), 640, 0, stream>>>(x, Ws, vsumT, sp);
    squash_kernel<2><<<320, 256, 0, stream>>>(sp, nullptr, out);
}

// Round 11
// 137.422 us; speedup vs baseline: 2.0982x; 2.0982x over previous
//
#include <hip/hip_runtime.h>

// SemanticCaps dynamic routing, fp32. B=128, J=10, K=1152, M=16, I=8.
// R16 = R9 champion (137.6 µs) + KB=3 barrier amortization:
//  - 3 k's per softmax barrier interval -> barriers/pass 9 -> 3, and THREE
//    independent wave-uniform Ws scalar-load chains per interval (the
//    ~102-SGPR file forces chunked s_load->waitcnt chains; 3 independent
//    chains interleave, dividing the chain stall).
//  - R11's pipelining failed because its prefetched FMAs sat BEFORE the
//    barrier, pinning the lgkmcnt drain there; KB-blocking is the
//    compiler-robust form of the same idea.
// Structure ranking measured across R5..R14: per-thread work per k wins
// (128 FMA/k = 24 µs > 80 FMA/k = 31 µs > 8 FMA/k = 98 µs) -> keep
// wave=j/lane=b. Falsified: LDS-Ws (R6), atomics (R4/R8), grid-sync
// (R3/R10), m-lane shuffles (R12/R13), thin-thread vector-Ws (R14).
// b-logit algebra: b after t iters = u.(v0+..+v_{t-1}) (b starts at 0).
//
// ws (floats): sp[128*10*128*16] v0T[20480] vsumT[20480]

#define B_ 128
#define J_ 10
#define K_ 1152
#define M_ 16
#define I_ 8
#define KT 9
#define KB 3                 // k's per barrier interval
#define NIV (KT / KB)        // 3 intervals per pass
#define NKT (K_ / KT)        // 128 k-tiles
#define RW (K_ * I_)         // 9216 floats per x batch-row
#define SVEC (J_ * B_ * M_)  // 20480 floats per fold-slice of sp
#define XT4 (KT * I_ / 4)    // 18 float4 per b-row of the x tile

// ---------- routing pass -----------------------------------------------------
// MODE 0: c == 1 (iteration 0; 0.1 folded into squash<0>)
// MODE 1: c = softmax_j(u . vin);  s = sum_k c*u
// Wave = output capsule j (10 waves), lane = batch b (64). Block stages its
// own 72x64 x-tile via LDS transpose. Per interval: compute u[0..2][16],
// logits, 3 earr writes, ONE barrier, 3 dens, accumulate. Interval-parity
// ping-pong on earr keeps reuse race-free with a single barrier.
template <int MODE>
__global__ __launch_bounds__(640)
void iter_kernel(const float* __restrict__ x, const float* __restrict__ Ws,
                 const float* __restrict__ vinT, float* __restrict__ sp) {
    __shared__ float xtile[KT * I_ * 64];       // 72 rows x 64 b = 18 KB
    __shared__ float earr[2][KB][J_ * 64];      // 15.4 KB, interval ping-pong
    const int t  = threadIdx.x;
    const int bl = t & 63;
    const int j  = __builtin_amdgcn_readfirstlane(t >> 6);  // wave-uniform j
    const int kt = blockIdx.x, bg = blockIdx.y;
    const int b  = bg * 64 + bl;

    // ---- stage + transpose x[bg*64..+64)[kt*72 .. +72) -> xtile[f][bb] -----
    {
        const float4* x4 = (const float4*)x;    // row stride RW/4 = 2304
        for (int idx = t; idx < 64 * XT4; idx += 640) {
            const int bb = idx / XT4, q = idx % XT4;
            const float4 w = x4[(size_t)(bg * 64 + bb) * (RW / 4) + kt * XT4 + q];
            xtile[(q * 4 + 0) * 64 + bb] = w.x;
            xtile[(q * 4 + 1) * 64 + bb] = w.y;
            xtile[(q * 4 + 2) * 64 + bb] = w.z;
            xtile[(q * 4 + 3) * 64 + bb] = w.w;
        }
    }

    float v[M_], s[M_];
#pragma unroll
    for (int m = 0; m < M_; ++m) s[m] = 0.f;
    if (MODE == 1) {
        const float4* vp = (const float4*)(vinT + ((size_t)j * B_ + b) * M_);
#pragma unroll
        for (int q = 0; q < 4; ++q) {
            const float4 w = vp[q];
            v[4*q] = w.x; v[4*q+1] = w.y; v[4*q+2] = w.z; v[4*q+3] = w.w;
        }
    }
    __syncthreads();   // x-tile ready

    const float* wb = Ws + ((size_t)j * K_ + (size_t)kt * KT) * (M_ * I_);

    for (int iv = 0; iv < NIV; ++iv) {
        const int par = iv & 1;
        float u[KB][M_];
        // ---- three independent u-computations (3 s_load chains interleave)
#pragma unroll
        for (int kb = 0; kb < KB; ++kb) {
            const int kk = iv * KB + kb;
            float xr[I_];
#pragma unroll
            for (int i = 0; i < I_; ++i)
                xr[i] = xtile[(kk * I_ + i) * 64 + bl];
            const float* w = wb + (size_t)kk * (M_ * I_);   // uniform -> s_load
#pragma unroll
            for (int m = 0; m < M_; ++m) {
                float a = 0.f;
#pragma unroll
                for (int i = 0; i < I_; ++i) a += w[m * I_ + i] * xr[i];
                u[kb][m] = a;
            }
        }

        if (MODE == 1) {
            float e[KB];
#pragma unroll
            for (int kb = 0; kb < KB; ++kb) {
                float lg = 0.f;
#pragma unroll
                for (int m = 0; m < M_; ++m) lg += u[kb][m] * v[m];
                e[kb] = __expf(lg);
                earr[par][kb][j * 64 + bl] = e[kb];
            }
            __syncthreads();   // ONE barrier per 3 k's; parity makes reuse safe
#pragma unroll
            for (int kb = 0; kb < KB; ++kb) {
                float den = 0.f;
#pragma unroll
                for (int jj = 0; jj < J_; ++jj)
                    den += earr[par][kb][jj * 64 + bl];
                const float c = __fdividef(e[kb], den);
#pragma unroll
                for (int m = 0; m < M_; ++m) s[m] = fmaf(c, u[kb][m], s[m]);
            }
        } else {
#pragma unroll
            for (int kb = 0; kb < KB; ++kb)
#pragma unroll
                for (int m = 0; m < M_; ++m) s[m] += u[kb][m];
        }
    }

    float4* o = (float4*)(sp + (((size_t)kt * J_ + j) * B_ + b) * M_);
#pragma unroll
    for (int q = 0; q < 4; ++q) {
        float4 w;
        w.x = s[4*q]; w.y = s[4*q+1]; w.z = s[4*q+2]; w.w = s[4*q+3];
        o[q] = w;
    }
}

// ---------- squash: parallel fold of 128 tile-partials, emit v ---------------
// 320 blocks x 256 thr; 4 waves each fold 32 slices for 64 outputs, LDS fold,
// wave 0 does the m-shuffle norm + emit.
// SM 0: v0T = squash(0.1*S)  SM 1: vsumT = v0T + squash(S)  SM 2: out = squash(S)
template <int SM>
__global__ __launch_bounds__(256)
void squash_kernel(const float* __restrict__ sp, const float* __restrict__ v0T,
                   float* __restrict__ dst) {
    __shared__ float red[4][64];
    const int t  = threadIdx.x;
    const int l  = t & 63;
    const int wv = t >> 6;
    const int g  = blockIdx.x * 64 + l;   // g = (j*128+b)*16+m
    const int m = g & 15;
    const int b = (g >> 4) & 127;
    const int j = g >> 11;
    const float* p = sp + (size_t)((j * B_ + b) * M_ + m);
    float S = 0.f;
#pragma unroll 8
    for (int tt = wv * (NKT / 4); tt < (wv + 1) * (NKT / 4); ++tt)
        S += p[(size_t)tt * SVEC];
    red[wv][l] = S;
    __syncthreads();
    if (wv == 0) {
        S = red[0][l] + red[1][l] + red[2][l] + red[3][l];
        if (SM == 0) S *= 0.1f;
        float sq = S * S;
        sq += __shfl_xor(sq, 1, 64);
        sq += __shfl_xor(sq, 2, 64);
        sq += __shfl_xor(sq, 4, 64);
        sq += __shfl_xor(sq, 8, 64);      // sum over m within 16-lane group
        const float n = sqrtf(sq);
        float v = S * (n / (1.f + sq));
        if (SM == 1) v += v0T[g];
        if (SM == 2) dst[((size_t)b * J_ + j) * M_ + m] = v;   // standard [b][j][m]
        else         dst[g] = v;                                // vT layout
    }
}

extern "C" void kernel_launch(void* const* d_in, const int* in_sizes, int n_in,
                              void* d_out, int out_size, void* d_ws, size_t ws_size,
                              hipStream_t stream) {
    const float* x  = (const float*)d_in[0];   // [128][1152][8]
    const float* Ws = (const float*)d_in[1];   // [10][1152][16][8]
    float* out = (float*)d_out;                // [128][10][16]

    float* sp    = (float*)d_ws;                           // 2,621,440 floats
    float* v0T   = sp + (size_t)NKT * SVEC;                //    20,480
    float* vsumT = v0T + SVEC;                             //    20,480

    iter_kernel<0><<<dim3(NKT, 2), 640, 0, stream>>>(x, Ws, nullptr, sp);
    squash_kernel<0><<<320, 256, 0, stream>>>(sp, nullptr, v0T);

    iter_kernel<1><<<dim3(NKT, 2), 640, 0, stream>>>(x, Ws, v0T, sp);
    squash_kernel<1><<<320, 256, 0, stream>>>(sp, v0T, vsumT);

    iter_kernel<1><<<dim3(NKT, 2), 640, 0, stream>>>(x, Ws, vsumT, sp);
    squash_kernel<2><<<320, 256, 0, stream>>>(sp, nullptr, out);
}